// Round 13
// baseline (87.135 us; speedup 1.0000x reference)
//
#include <hip/hip_runtime.h>

typedef __attribute__((ext_vector_type(8))) short bf16x8;
typedef __attribute__((ext_vector_type(4))) float f32x4;
typedef __attribute__((ext_vector_type(8))) unsigned short u16x8;

__device__ __forceinline__ unsigned short f2bf(float f) {
  union { float f; unsigned u; } v; v.f = f;
  unsigned r = v.u + 0x7FFF + ((v.u >> 16) & 1);
  return (unsigned short)(r >> 16);
}
__device__ __forceinline__ float bf2f(unsigned short s) {
  union { unsigned u; float f; } v; v.u = ((unsigned)s) << 16;
  return v.f;
}

// W[m][n][k] f32 -> Wt[m][k][n] bf16 (no swizzle; W is consumed via
// register loads now, not LDS).
__global__ __launch_bounds__(256) void transpose_w(const float* __restrict__ W1,
                                                   const float* __restrict__ W2,
                                                   unsigned short* __restrict__ W1t,
                                                   unsigned short* __restrict__ W2t) {
  __shared__ float ws_[64 * 64];
  const int m = blockIdx.x & 63, sel = blockIdx.x >> 6;
  const float* src = (sel ? W2 : W1) + m * 4096;
  unsigned short* dst = (sel ? W2t : W1t) + m * 4096;
  const int t = threadIdx.x;
  #pragma unroll
  for (int i = 0; i < 4; ++i) {
    const int idx = i * 256 + t;
    *(float4*)&ws_[idx << 2] = *(const float4*)&src[idx << 2];
  }
  __syncthreads();
  #pragma unroll
  for (int j = 0; j < 2; ++j) {
    const int idx = j * 256 + t;
    const int k = idx >> 3, g = idx & 7;
    u16x8 o;
    #pragma unroll
    for (int jj = 0; jj < 8; ++jj) o[jj] = f2bf(ws_[(((g << 3) + jj) << 6) + k]);
    *(u16x8*)&dst[(k << 6) + (g << 3)] = o;
  }
}

// One layer, register-direct W: per m, each wave loads its own A-fragments
// (2 x 16B, wave-private k-rows -> zero cross-wave duplication) straight from
// global; compiler pipelines ~8 m ahead. No barriers, no LDS staging for W.
__device__ __forceinline__ void layer_pass(
    const unsigned short* __restrict__ Wt,
    const unsigned short* u_lds, const bf16x8 (&Bf)[2][2],
    f32x4& acc0, f32x4& acc1, int aoffg, int uoff0, int uoff1) {
  acc0 = (f32x4){0.f, 0.f, 0.f, 0.f};
  acc1 = (f32x4){0.f, 0.f, 0.f, 0.f};
  #pragma unroll 8
  for (int m = 0; m < 64; ++m) {
    const unsigned short* wp = Wt + m * 4096 + aoffg;
    bf16x8 a0 = *(const bf16x8*)(wp);
    bf16x8 a1 = *(const bf16x8*)(wp + 32);
    f32x4 t0 = {0.f, 0.f, 0.f, 0.f}, t1 = {0.f, 0.f, 0.f, 0.f};
    t0 = __builtin_amdgcn_mfma_f32_16x16x32_bf16(a0, Bf[0][0], t0, 0, 0, 0);
    t0 = __builtin_amdgcn_mfma_f32_16x16x32_bf16(a1, Bf[0][1], t0, 0, 0, 0);
    t1 = __builtin_amdgcn_mfma_f32_16x16x32_bf16(a0, Bf[1][0], t1, 0, 0, 0);
    t1 = __builtin_amdgcn_mfma_f32_16x16x32_bf16(a1, Bf[1][1], t1, 0, 0, 0);
    const float u0 = bf2f(u_lds[m * 64 + uoff0]);
    const float u1 = bf2f(u_lds[m * 64 + uoff1]);
    #pragma unroll
    for (int r = 0; r < 4; ++r) {
      acc0[r] += u0 * t0[r];
      acc1[r] += u1 * t1[r];
    }
  }
}

// Fused cross layers. Block = (b, 64-d tile); 256 blocks, 512 threads
// = 8 waves = 4 kt x 2 dh. LDS: only u_lds[64][64] bf16 (8KB).
__global__ __launch_bounds__(512) void fused_layers(
    const float* __restrict__ x,
    const unsigned short* __restrict__ W1t, const unsigned short* __restrict__ W2t,
    unsigned short* __restrict__ X1kd, unsigned short* __restrict__ X2kd) {
  __shared__ unsigned short u_lds[64 * 64];

  const int t = threadIdx.x;
  const int l = t & 63, w = t >> 6;
  const int kt = w & 3, dh = w >> 2;
  const int b = blockIdx.x >> 3, d0 = (blockIdx.x & 7) << 6;
  const int l15 = l & 15, lg = l >> 4;

  // stage u1 = bf16(x[b, m, d-tile]) -> u_lds[m][dl]
  {
    const int m = t >> 3, ch = t & 7;
    const float* src = x + ((b << 6) + m) * 512 + d0 + (ch << 3);
    float4 a = *(const float4*)src;
    float4 c4 = *(const float4*)(src + 4);
    u16x8 o;
    o[0] = f2bf(a.x); o[1] = f2bf(a.y); o[2] = f2bf(a.z); o[3] = f2bf(a.w);
    o[4] = f2bf(c4.x); o[5] = f2bf(c4.y); o[6] = f2bf(c4.z); o[7] = f2bf(c4.w);
    *(u16x8*)&u_lds[(m << 6) + (ch << 3)] = o;
  }

  // B fragments from x (V = X0 both layers)
  bf16x8 Bf[2][2];
  {
    const float* xb = x + (b << 6) * 512 + d0 + dh * 32 + l15;
    #pragma unroll
    for (int dt = 0; dt < 2; ++dt)
      #pragma unroll
      for (int h = 0; h < 2; ++h) {
        bf16x8 o;
        #pragma unroll
        for (int jj = 0; jj < 8; ++jj)
          o[jj] = (short)f2bf(xb[(h * 32 + lg * 8 + jj) * 512 + dt * 16]);
        Bf[dt][h] = o;
      }
  }

  const int aoffg = (kt * 16 + l15) * 64 + lg * 8;  // A-frag global offset in Wt m-slice
  const int uoff0 = dh * 32 + l15;
  const int uoff1 = dh * 32 + 16 + l15;

  __syncthreads();  // u_lds ready

  f32x4 acc0, acc1;

  // ---- layer 1 ----
  layer_pass(W1t, u_lds, Bf, acc0, acc1, aoffg, uoff0, uoff1);

  __syncthreads();  // all u_lds reads done before overwrite

  // epilogue 1: relu -> X1kd (global) AND u_lds (layer-2 u).
  #pragma unroll
  for (int dt = 0; dt < 2; ++dt) {
    const f32x4 a = dt ? acc1 : acc0;
    #pragma unroll
    for (int r = 0; r < 4; ++r) {
      const int k = kt * 16 + lg * 4 + r;
      const int dl = dh * 32 + dt * 16 + l15;
      const unsigned short hv = f2bf(fmaxf(a[r], 0.f));
      X1kd[((b << 6) + k) * 512 + d0 + dl] = hv;
      u_lds[k * 64 + dl] = hv;
    }
  }

  __syncthreads();  // u2 visible

  // ---- layer 2 ----
  layer_pass(W2t, u_lds, Bf, acc0, acc1, aoffg, uoff0, uoff1);

  // epilogue 2
  #pragma unroll
  for (int dt = 0; dt < 2; ++dt) {
    const f32x4 a = dt ? acc1 : acc0;
    #pragma unroll
    for (int r = 0; r < 4; ++r) {
      const int k = kt * 16 + lg * 4 + r;
      const int dl = dh * 32 + dt * 16 + l15;
      X2kd[((b << 6) + k) * 512 + d0 + dl] = f2bf(fmaxf(a[r], 0.f));
    }
  }
}

// out[b,p,d] = LN_d( x[b,p,d] + pb[p] + sum_t pw[p,t]*X1kd[b][t][d] + pw[p,64+t]*X2kd[b][t][d] )
// grid 512 = (b, 16 groups of 4 p); 512 threads = d. 2 blocks/CU.
__global__ __launch_bounds__(512) void proj_ln(
    const float* __restrict__ x, const unsigned short* __restrict__ X1kd,
    const unsigned short* __restrict__ X2kd, const float* __restrict__ pw,
    const float* __restrict__ pb, const float* __restrict__ gamma,
    const float* __restrict__ beta, float* __restrict__ out) {
  const int b = blockIdx.x >> 4, pg = blockIdx.x & 15;
  const int d = threadIdx.x;
  __shared__ float red[4 * 16];

  float s[4] = {0.f, 0.f, 0.f, 0.f};
  const float* pwb = pw + pg * 4 * 128;  // block-uniform rows
  const unsigned short* r1 = X1kd + (b << 6) * 512 + d;
  const unsigned short* r2 = X2kd + (b << 6) * 512 + d;

  #pragma unroll 4
  for (int tt = 0; tt < 64; ++tt) {
    const float c = bf2f(r1[tt * 512]);
    #pragma unroll
    for (int pi = 0; pi < 4; ++pi) s[pi] += pwb[pi * 128 + tt] * c;
  }
  #pragma unroll 4
  for (int tt = 0; tt < 64; ++tt) {
    const float c = bf2f(r2[tt * 512]);
    #pragma unroll
    for (int pi = 0; pi < 4; ++pi) s[pi] += pwb[pi * 128 + 64 + tt] * c;
  }

  const int wv = d >> 6, ln = d & 63;
  float yv[4];
  #pragma unroll
  for (int pi = 0; pi < 4; ++pi) {
    const int p = pg * 4 + pi;
    const float y = x[((b << 6) + p) * 512 + d] + pb[p] + s[pi];
    yv[pi] = y;
    float sm = y, sq = y * y;
    #pragma unroll
    for (int off = 32; off > 0; off >>= 1) {
      sm += __shfl_xor(sm, off);
      sq += __shfl_xor(sq, off);
    }
    if (ln == 0) { red[pi * 16 + wv] = sm; red[pi * 16 + 8 + wv] = sq; }
  }
  __syncthreads();

  const float gam = gamma[d], bet = beta[d];
  #pragma unroll
  for (int pi = 0; pi < 4; ++pi) {
    float sum = 0.f, sumsq = 0.f;
    #pragma unroll
    for (int j = 0; j < 8; ++j) { sum += red[pi * 16 + j]; sumsq += red[pi * 16 + 8 + j]; }
    const float mu = sum * (1.f / 512.f);
    const float var = sumsq * (1.f / 512.f) - mu * mu;
    const float rs = rsqrtf(var + 1e-5f);
    const int p = pg * 4 + pi;
    out[((b << 6) + p) * 512 + d] = gam * (yv[pi] - mu) * rs + bet;
  }
}

extern "C" void kernel_launch(void* const* d_in, const int* in_sizes, int n_in,
                              void* d_out, int out_size, void* d_ws, size_t ws_size,
                              hipStream_t stream) {
  const float* x     = (const float*)d_in[0];
  const float* W1    = (const float*)d_in[1];
  const float* W2    = (const float*)d_in[2];
  const float* pw    = (const float*)d_in[3];
  const float* pb    = (const float*)d_in[4];
  const float* gamma = (const float*)d_in[5];
  const float* beta  = (const float*)d_in[6];
  float* out = (float*)d_out;

  char* ws = (char*)d_ws;
  unsigned short* X1kd = (unsigned short*)(ws);                          // 2MB [32][64][512]
  unsigned short* X2kd = (unsigned short*)(ws + (2u << 20));             // 2MB [32][64][512]
  unsigned short* W1t  = (unsigned short*)(ws + (4u << 20));             // 512KB [m][k][n]
  unsigned short* W2t  = (unsigned short*)(ws + (4u << 20) + (512u << 10));

  transpose_w<<<dim3(128), dim3(256), 0, stream>>>(W1, W2, W1t, W2t);
  fused_layers<<<dim3(256), dim3(512), 0, stream>>>(x, W1t, W2t, X1kd, X2kd);
  proj_ln<<<dim3(512), dim3(512), 0, stream>>>(x, X1kd, X2kd, pw, pb, gamma, beta, out);
}

// Round 14
// 86.849 us; speedup vs baseline: 1.0033x; 1.0033x over previous
//
#include <hip/hip_runtime.h>

typedef __attribute__((ext_vector_type(8))) short bf16x8;
typedef __attribute__((ext_vector_type(4))) float f32x4;
typedef __attribute__((ext_vector_type(8))) unsigned short u16x8;

__device__ __forceinline__ unsigned short f2bf(float f) {
  union { float f; unsigned u; } v; v.f = f;
  unsigned r = v.u + 0x7FFF + ((v.u >> 16) & 1);
  return (unsigned short)(r >> 16);
}
__device__ __forceinline__ float bf2f(unsigned short s) {
  union { unsigned u; float f; } v; v.u = ((unsigned)s) << 16;
  return v.f;
}

// W[m][n][k] f32 -> Wt[m][k][n] bf16 (register-direct consumption; no swizzle)
__global__ __launch_bounds__(256) void transpose_w(const float* __restrict__ W1,
                                                   const float* __restrict__ W2,
                                                   unsigned short* __restrict__ W1t,
                                                   unsigned short* __restrict__ W2t) {
  __shared__ float ws_[64 * 64];
  const int m = blockIdx.x & 63, sel = blockIdx.x >> 6;
  const float* src = (sel ? W2 : W1) + m * 4096;
  unsigned short* dst = (sel ? W2t : W1t) + m * 4096;
  const int t = threadIdx.x;
  #pragma unroll
  for (int i = 0; i < 4; ++i) {
    const int idx = i * 256 + t;
    *(float4*)&ws_[idx << 2] = *(const float4*)&src[idx << 2];
  }
  __syncthreads();
  #pragma unroll
  for (int j = 0; j < 2; ++j) {
    const int idx = j * 256 + t;
    const int k = idx >> 3, g = idx & 7;
    u16x8 o;
    #pragma unroll
    for (int jj = 0; jj < 8; ++jj) o[jj] = f2bf(ws_[(((g << 3) + jj) << 6) + k]);
    *(u16x8*)&dst[(k << 6) + (g << 3)] = o;
  }
}

// One layer, register-direct W with EXPLICIT distance-4 prefetch rotation.
// Loop fully unrolled -> pa[m&3] indices are compile-time static (stay in
// VGPRs, rule #20). Loads for m+4 issue BEFORE m's MFMAs: 8 loads in
// flight/wave x 8 waves = 64/CU, covering ~200cyc L2 latency several times.
__device__ __forceinline__ void layer_pass(
    const unsigned short* __restrict__ Wt,
    const unsigned short* u_lds, const bf16x8 (&Bf)[2][2],
    f32x4& acc0, f32x4& acc1, int aoffg, int uoff0, int uoff1) {
  acc0 = (f32x4){0.f, 0.f, 0.f, 0.f};
  acc1 = (f32x4){0.f, 0.f, 0.f, 0.f};

  bf16x8 pa0[4], pa1[4];
  #pragma unroll
  for (int i = 0; i < 4; ++i) {
    const unsigned short* wp = Wt + i * 4096 + aoffg;
    pa0[i] = *(const bf16x8*)(wp);
    pa1[i] = *(const bf16x8*)(wp + 32);
  }

  #pragma unroll
  for (int m = 0; m < 64; ++m) {
    const bf16x8 a0 = pa0[m & 3];
    const bf16x8 a1 = pa1[m & 3];
    if (m < 60) {  // issue m+4's loads now; consumed 4 iterations later
      const unsigned short* wp = Wt + (m + 4) * 4096 + aoffg;
      pa0[m & 3] = *(const bf16x8*)(wp);
      pa1[m & 3] = *(const bf16x8*)(wp + 32);
    }
    f32x4 t0 = {0.f, 0.f, 0.f, 0.f}, t1 = {0.f, 0.f, 0.f, 0.f};
    t0 = __builtin_amdgcn_mfma_f32_16x16x32_bf16(a0, Bf[0][0], t0, 0, 0, 0);
    t0 = __builtin_amdgcn_mfma_f32_16x16x32_bf16(a1, Bf[0][1], t0, 0, 0, 0);
    t1 = __builtin_amdgcn_mfma_f32_16x16x32_bf16(a0, Bf[1][0], t1, 0, 0, 0);
    t1 = __builtin_amdgcn_mfma_f32_16x16x32_bf16(a1, Bf[1][1], t1, 0, 0, 0);
    const float u0 = bf2f(u_lds[m * 64 + uoff0]);
    const float u1 = bf2f(u_lds[m * 64 + uoff1]);
    #pragma unroll
    for (int r = 0; r < 4; ++r) {
      acc0[r] += u0 * t0[r];
      acc1[r] += u1 * t1[r];
    }
  }
}

// Fused cross layers. Block = (b, 64-d tile); 256 blocks, 512 threads
// = 8 waves = 4 kt x 2 dh. LDS: only u_lds[64][64] bf16 (8KB).
__global__ __launch_bounds__(512) void fused_layers(
    const float* __restrict__ x,
    const unsigned short* __restrict__ W1t, const unsigned short* __restrict__ W2t,
    unsigned short* __restrict__ X1kd, unsigned short* __restrict__ X2kd) {
  __shared__ unsigned short u_lds[64 * 64];

  const int t = threadIdx.x;
  const int l = t & 63, w = t >> 6;
  const int kt = w & 3, dh = w >> 2;
  const int b = blockIdx.x >> 3, d0 = (blockIdx.x & 7) << 6;
  const int l15 = l & 15, lg = l >> 4;

  // stage u1 = bf16(x[b, m, d-tile]) -> u_lds[m][dl]
  {
    const int m = t >> 3, ch = t & 7;
    const float* src = x + ((b << 6) + m) * 512 + d0 + (ch << 3);
    float4 a = *(const float4*)src;
    float4 c4 = *(const float4*)(src + 4);
    u16x8 o;
    o[0] = f2bf(a.x); o[1] = f2bf(a.y); o[2] = f2bf(a.z); o[3] = f2bf(a.w);
    o[4] = f2bf(c4.x); o[5] = f2bf(c4.y); o[6] = f2bf(c4.z); o[7] = f2bf(c4.w);
    *(u16x8*)&u_lds[(m << 6) + (ch << 3)] = o;
  }

  // B fragments from x (V = X0 both layers)
  bf16x8 Bf[2][2];
  {
    const float* xb = x + (b << 6) * 512 + d0 + dh * 32 + l15;
    #pragma unroll
    for (int dt = 0; dt < 2; ++dt)
      #pragma unroll
      for (int h = 0; h < 2; ++h) {
        bf16x8 o;
        #pragma unroll
        for (int jj = 0; jj < 8; ++jj)
          o[jj] = (short)f2bf(xb[(h * 32 + lg * 8 + jj) * 512 + dt * 16]);
        Bf[dt][h] = o;
      }
  }

  const int aoffg = (kt * 16 + l15) * 64 + lg * 8;  // A-frag offset in Wt m-slice
  const int uoff0 = dh * 32 + l15;
  const int uoff1 = dh * 32 + 16 + l15;

  __syncthreads();  // u_lds ready

  f32x4 acc0, acc1;

  // ---- layer 1 ----
  layer_pass(W1t, u_lds, Bf, acc0, acc1, aoffg, uoff0, uoff1);

  __syncthreads();  // all u_lds reads done before overwrite

  // epilogue 1: relu -> X1kd (global) AND u_lds (layer-2 u).
  #pragma unroll
  for (int dt = 0; dt < 2; ++dt) {
    const f32x4 a = dt ? acc1 : acc0;
    #pragma unroll
    for (int r = 0; r < 4; ++r) {
      const int k = kt * 16 + lg * 4 + r;
      const int dl = dh * 32 + dt * 16 + l15;
      const unsigned short hv = f2bf(fmaxf(a[r], 0.f));
      X1kd[((b << 6) + k) * 512 + d0 + dl] = hv;
      u_lds[k * 64 + dl] = hv;
    }
  }

  __syncthreads();  // u2 visible

  // ---- layer 2 ----
  layer_pass(W2t, u_lds, Bf, acc0, acc1, aoffg, uoff0, uoff1);

  // epilogue 2
  #pragma unroll
  for (int dt = 0; dt < 2; ++dt) {
    const f32x4 a = dt ? acc1 : acc0;
    #pragma unroll
    for (int r = 0; r < 4; ++r) {
      const int k = kt * 16 + lg * 4 + r;
      const int dl = dh * 32 + dt * 16 + l15;
      X2kd[((b << 6) + k) * 512 + d0 + dl] = f2bf(fmaxf(a[r], 0.f));
    }
  }
}

// out[b,p,d] = LN_d( x[b,p,d] + pb[p] + sum_t pw[p,t]*X1kd[b][t][d] + pw[p,64+t]*X2kd[b][t][d] )
// grid 512 = (b, 16 groups of 4 p); 512 threads = d. 2 blocks/CU.
__global__ __launch_bounds__(512) void proj_ln(
    const float* __restrict__ x, const unsigned short* __restrict__ X1kd,
    const unsigned short* __restrict__ X2kd, const float* __restrict__ pw,
    const float* __restrict__ pb, const float* __restrict__ gamma,
    const float* __restrict__ beta, float* __restrict__ out) {
  const int b = blockIdx.x >> 4, pg = blockIdx.x & 15;
  const int d = threadIdx.x;
  __shared__ float red[4 * 16];

  float s[4] = {0.f, 0.f, 0.f, 0.f};
  const float* pwb = pw + pg * 4 * 128;  // block-uniform rows
  const unsigned short* r1 = X1kd + (b << 6) * 512 + d;
  const unsigned short* r2 = X2kd + (b << 6) * 512 + d;

  #pragma unroll 4
  for (int tt = 0; tt < 64; ++tt) {
    const float c = bf2f(r1[tt * 512]);
    #pragma unroll
    for (int pi = 0; pi < 4; ++pi) s[pi] += pwb[pi * 128 + tt] * c;
  }
  #pragma unroll 4
  for (int tt = 0; tt < 64; ++tt) {
    const float c = bf2f(r2[tt * 512]);
    #pragma unroll
    for (int pi = 0; pi < 4; ++pi) s[pi] += pwb[pi * 128 + 64 + tt] * c;
  }

  const int wv = d >> 6, ln = d & 63;
  float yv[4];
  #pragma unroll
  for (int pi = 0; pi < 4; ++pi) {
    const int p = pg * 4 + pi;
    const float y = x[((b << 6) + p) * 512 + d] + pb[p] + s[pi];
    yv[pi] = y;
    float sm = y, sq = y * y;
    #pragma unroll
    for (int off = 32; off > 0; off >>= 1) {
      sm += __shfl_xor(sm, off);
      sq += __shfl_xor(sq, off);
    }
    if (ln == 0) { red[pi * 16 + wv] = sm; red[pi * 16 + 8 + wv] = sq; }
  }
  __syncthreads();

  const float gam = gamma[d], bet = beta[d];
  #pragma unroll
  for (int pi = 0; pi < 4; ++pi) {
    float sum = 0.f, sumsq = 0.f;
    #pragma unroll
    for (int j = 0; j < 8; ++j) { sum += red[pi * 16 + j]; sumsq += red[pi * 16 + 8 + j]; }
    const float mu = sum * (1.f / 512.f);
    const float var = sumsq * (1.f / 512.f) - mu * mu;
    const float rs = rsqrtf(var + 1e-5f);
    const int p = pg * 4 + pi;
    out[((b << 6) + p) * 512 + d] = gam * (yv[pi] - mu) * rs + bet;
  }
}

extern "C" void kernel_launch(void* const* d_in, const int* in_sizes, int n_in,
                              void* d_out, int out_size, void* d_ws, size_t ws_size,
                              hipStream_t stream) {
  const float* x     = (const float*)d_in[0];
  const float* W1    = (const float*)d_in[1];
  const float* W2    = (const float*)d_in[2];
  const float* pw    = (const float*)d_in[3];
  const float* pb    = (const float*)d_in[4];
  const float* gamma = (const float*)d_in[5];
  const float* beta  = (const float*)d_in[6];
  float* out = (float*)d_out;

  char* ws = (char*)d_ws;
  unsigned short* X1kd = (unsigned short*)(ws);                          // 2MB [32][64][512]
  unsigned short* X2kd = (unsigned short*)(ws + (2u << 20));             // 2MB [32][64][512]
  unsigned short* W1t  = (unsigned short*)(ws + (4u << 20));             // 512KB [m][k][n]
  unsigned short* W2t  = (unsigned short*)(ws + (4u << 20) + (512u << 10));

  transpose_w<<<dim3(128), dim3(256), 0, stream>>>(W1, W2, W1t, W2t);
  fused_layers<<<dim3(256), dim3(512), 0, stream>>>(x, W1t, W2t, X1kd, X2kd);
  proj_ln<<<dim3(512), dim3(512), 0, stream>>>(x, X1kd, X2kd, pw, pb, gamma, beta, out);
}

// Round 15
// 53.137 us; speedup vs baseline: 1.6398x; 1.6344x over previous
//
#include <hip/hip_runtime.h>

typedef __attribute__((ext_vector_type(8))) short bf16x8;
typedef __attribute__((ext_vector_type(4))) float f32x4;
typedef __attribute__((ext_vector_type(8))) unsigned short u16x8;

__device__ __forceinline__ unsigned short f2bf(float f) {
  union { float f; unsigned u; } v; v.f = f;
  unsigned r = v.u + 0x7FFF + ((v.u >> 16) & 1);
  return (unsigned short)(r >> 16);
}
__device__ __forceinline__ float bf2f(unsigned short s) {
  union { unsigned u; float f; } v; v.u = ((unsigned)s) << 16;
  return v.f;
}
__device__ __forceinline__ void gll16(const unsigned short* g, unsigned short* l) {
  __builtin_amdgcn_global_load_lds(
      (const __attribute__((address_space(1))) void*)g,
      (__attribute__((address_space(3))) void*)l, 16, 0, 0);
}

// W[m][n][k] f32 -> Wt[m][k][n] bf16, 16B-chunk XOR swizzle: slot = g ^ (k&7)
__global__ __launch_bounds__(256) void transpose_w(const float* __restrict__ W1,
                                                   const float* __restrict__ W2,
                                                   unsigned short* __restrict__ W1t,
                                                   unsigned short* __restrict__ W2t) {
  __shared__ float ws_[64 * 64];
  const int m = blockIdx.x & 63, sel = blockIdx.x >> 6;
  const float* src = (sel ? W2 : W1) + m * 4096;
  unsigned short* dst = (sel ? W2t : W1t) + m * 4096;
  const int t = threadIdx.x;
  #pragma unroll
  for (int i = 0; i < 4; ++i) {
    const int idx = i * 256 + t;
    *(float4*)&ws_[idx << 2] = *(const float4*)&src[idx << 2];
  }
  __syncthreads();
  #pragma unroll
  for (int j = 0; j < 2; ++j) {
    const int idx = j * 256 + t;
    const int k = idx >> 3, g = idx & 7;
    u16x8 o;
    #pragma unroll
    for (int jj = 0; jj < 8; ++jj) o[jj] = f2bf(ws_[(((g << 3) + jj) << 6) + k]);
    const int slot = g ^ (k & 7);
    *(u16x8*)&dst[(k << 6) + (slot << 3)] = o;
  }
}

// One layer: 16 chunks of 4 m-slices (32KB) through a 2-buffer ping-pong.
// 4-wave block; the CU hosts TWO independent blocks, so one block's
// vmcnt/barrier stalls are covered by the other block's waves (m97 geometry).
// Per iter: issue c+1 (8 gll16/thread) -> compute c -> vmcnt(0) -> s_barrier.
__device__ __forceinline__ void layer_pass(
    const unsigned short* __restrict__ Wt, unsigned short* wbuf,
    const unsigned short* u_lds, const bf16x8 (&Bf)[2][2],
    f32x4& acc0, f32x4& acc1,
    int aoff0, int aoff1, int uoff0, int uoff1, int t) {
  // prologue: chunk 0 -> buf0; wait publishes u_lds writes too; barrier.
  #pragma unroll
  for (int j = 0; j < 8; ++j) gll16(Wt + j * 2048 + t * 8, wbuf + j * 2048 + t * 8);
  __builtin_amdgcn_sched_barrier(0);
  asm volatile("s_waitcnt vmcnt(0) lgkmcnt(0)" ::: "memory");
  __builtin_amdgcn_sched_barrier(0);
  __builtin_amdgcn_s_barrier();
  __builtin_amdgcn_sched_barrier(0);

  acc0 = (f32x4){0.f, 0.f, 0.f, 0.f};
  acc1 = (f32x4){0.f, 0.f, 0.f, 0.f};

  for (int c = 0; c < 16; ++c) {
    if (c < 15) {  // issue chunk c+1 into the other buffer
      const unsigned short* wsrc = Wt + (c + 1) * 16384;
      unsigned short* dst = wbuf + ((c + 1) & 1) * 16384;
      #pragma unroll
      for (int j = 0; j < 8; ++j) gll16(wsrc + j * 2048 + t * 8, dst + j * 2048 + t * 8);
    }
    const unsigned short* bufc = wbuf + (c & 1) * 16384;
    #pragma unroll
    for (int mm = 0; mm < 4; ++mm) {
      const int m = (c << 2) + mm;
      bf16x8 a0 = *(const bf16x8*)(bufc + mm * 4096 + aoff0);
      bf16x8 a1 = *(const bf16x8*)(bufc + mm * 4096 + aoff1);
      f32x4 t0 = {0.f, 0.f, 0.f, 0.f}, t1 = {0.f, 0.f, 0.f, 0.f};
      t0 = __builtin_amdgcn_mfma_f32_16x16x32_bf16(a0, Bf[0][0], t0, 0, 0, 0);
      t0 = __builtin_amdgcn_mfma_f32_16x16x32_bf16(a1, Bf[0][1], t0, 0, 0, 0);
      t1 = __builtin_amdgcn_mfma_f32_16x16x32_bf16(a0, Bf[1][0], t1, 0, 0, 0);
      t1 = __builtin_amdgcn_mfma_f32_16x16x32_bf16(a1, Bf[1][1], t1, 0, 0, 0);
      const float u0 = bf2f(u_lds[m * 32 + uoff0]);
      const float u1 = bf2f(u_lds[m * 32 + uoff1]);
      #pragma unroll
      for (int r = 0; r < 4; ++r) {
        acc0[r] += u0 * t0[r];
        acc1[r] += u1 * t1[r];
      }
    }
    if (c < 15) {
      __builtin_amdgcn_sched_barrier(0);
      asm volatile("s_waitcnt vmcnt(0)" ::: "memory");  // chunk c+1 landed
      __builtin_amdgcn_sched_barrier(0);
      __builtin_amdgcn_s_barrier();
      __builtin_amdgcn_sched_barrier(0);
    }
  }
  __syncthreads();  // all waves done with wbuf + u_lds before epilogue rewrites
}

// Fused cross layers. Block = (b, 32-d tile); 512 blocks, 256 threads
// = 4 waves (kt = 0..3; each wave 16k x 32d via 2 dt fragments).
// Dynamic LDS: wbuf[2][32KB] | u_lds[64][32] bf16 (4KB) = 69632 B -> 2 blocks/CU.
__global__ __launch_bounds__(256, 2) void fused_layers(
    const float* __restrict__ x,
    const unsigned short* __restrict__ W1t, const unsigned short* __restrict__ W2t,
    unsigned short* __restrict__ X1kd, unsigned short* __restrict__ X2kd) {
  extern __shared__ char smem[];
  unsigned short* wbuf = (unsigned short*)smem;              // 2*16384 shorts
  unsigned short* u_lds = (unsigned short*)(smem + 65536);   // [m][32]

  const int t = threadIdx.x;
  const int l = t & 63, kt = t >> 6;
  const int b = blockIdx.x >> 4, d0 = (blockIdx.x & 15) << 5;
  const int l15 = l & 15, lg = l >> 4;

  // stage u1 = bf16(x[b, m, d-tile]) -> u_lds[m][dl]  (8 cols per thread)
  {
    const int m = t >> 2, ch = t & 3;
    const float* src = x + ((b << 6) + m) * 512 + d0 + (ch << 3);
    float4 a = *(const float4*)src;
    float4 c4 = *(const float4*)(src + 4);
    u16x8 o;
    o[0] = f2bf(a.x); o[1] = f2bf(a.y); o[2] = f2bf(a.z); o[3] = f2bf(a.w);
    o[4] = f2bf(c4.x); o[5] = f2bf(c4.y); o[6] = f2bf(c4.z); o[7] = f2bf(c4.w);
    *(u16x8*)&u_lds[(m << 5) + (ch << 3)] = o;
  }
  __syncthreads();  // u_lds ready (also feeds Bf below)

  // B fragments from u_lds (v = x for BOTH layers; u_lds holds exactly
  // x[b, :, d-tile]): Bf[dt][h][jj] = x[b, h*32+lg*8+jj, d0+dt*16+l15]
  bf16x8 Bf[2][2];
  #pragma unroll
  for (int dt = 0; dt < 2; ++dt)
    #pragma unroll
    for (int h = 0; h < 2; ++h) {
      bf16x8 o;
      #pragma unroll
      for (int jj = 0; jj < 8; ++jj)
        o[jj] = (short)u_lds[((h * 32 + lg * 8 + jj) << 5) + dt * 16 + l15];
      Bf[dt][h] = o;
    }

  const int krow = kt * 16 + l15;
  const int kx = krow & 7;
  const int aoff0 = krow * 64 + ((0 + lg) ^ kx) * 8;
  const int aoff1 = krow * 64 + ((4 + lg) ^ kx) * 8;
  const int uoff0 = l15;        // dt=0 d-col
  const int uoff1 = 16 + l15;   // dt=1 d-col

  f32x4 acc0, acc1;

  // ---- layer 1 ----
  layer_pass(W1t, wbuf, u_lds, Bf, acc0, acc1, aoff0, aoff1, uoff0, uoff1, t);

  // epilogue 1: relu -> X1kd (global) AND u_lds (layer-2 u). Disjoint slots.
  #pragma unroll
  for (int dt = 0; dt < 2; ++dt) {
    const f32x4 a = dt ? acc1 : acc0;
    #pragma unroll
    for (int r = 0; r < 4; ++r) {
      const int k = kt * 16 + lg * 4 + r;
      const int dl = dt * 16 + l15;
      const unsigned short hv = f2bf(fmaxf(a[r], 0.f));
      X1kd[((b << 6) + k) * 512 + d0 + dl] = hv;
      u_lds[(k << 5) + dl] = hv;
    }
  }
  // layer-2 prologue waits vmcnt(0) lgkmcnt(0) + barrier -> stores drained,
  // u_lds writes visible block-wide before any wave computes.

  // ---- layer 2 ----
  layer_pass(W2t, wbuf, u_lds, Bf, acc0, acc1, aoff0, aoff1, uoff0, uoff1, t);

  // epilogue 2
  #pragma unroll
  for (int dt = 0; dt < 2; ++dt) {
    const f32x4 a = dt ? acc1 : acc0;
    #pragma unroll
    for (int r = 0; r < 4; ++r) {
      const int k = kt * 16 + lg * 4 + r;
      const int dl = dt * 16 + l15;
      X2kd[((b << 6) + k) * 512 + d0 + dl] = f2bf(fmaxf(a[r], 0.f));
    }
  }
}

// out[b,p,d] = LN_d( x[b,p,d] + pb[p] + sum_t pw[p,t]*X1kd[b][t][d] + pw[p,64+t]*X2kd[b][t][d] )
// grid 512 = (b, 16 groups of 4 p); 512 threads = d. 2 blocks/CU.
__global__ __launch_bounds__(512) void proj_ln(
    const float* __restrict__ x, const unsigned short* __restrict__ X1kd,
    const unsigned short* __restrict__ X2kd, const float* __restrict__ pw,
    const float* __restrict__ pb, const float* __restrict__ gamma,
    const float* __restrict__ beta, float* __restrict__ out) {
  const int b = blockIdx.x >> 4, pg = blockIdx.x & 15;
  const int d = threadIdx.x;
  __shared__ float red[4 * 16];

  float s[4] = {0.f, 0.f, 0.f, 0.f};
  const float* pwb = pw + pg * 4 * 128;  // block-uniform rows
  const unsigned short* r1 = X1kd + (b << 6) * 512 + d;
  const unsigned short* r2 = X2kd + (b << 6) * 512 + d;

  #pragma unroll 4
  for (int tt = 0; tt < 64; ++tt) {
    const float c = bf2f(r1[tt * 512]);
    #pragma unroll
    for (int pi = 0; pi < 4; ++pi) s[pi] += pwb[pi * 128 + tt] * c;
  }
  #pragma unroll 4
  for (int tt = 0; tt < 64; ++tt) {
    const float c = bf2f(r2[tt * 512]);
    #pragma unroll
    for (int pi = 0; pi < 4; ++pi) s[pi] += pwb[pi * 128 + 64 + tt] * c;
  }

  const int wv = d >> 6, ln = d & 63;
  float yv[4];
  #pragma unroll
  for (int pi = 0; pi < 4; ++pi) {
    const int p = pg * 4 + pi;
    const float y = x[((b << 6) + p) * 512 + d] + pb[p] + s[pi];
    yv[pi] = y;
    float sm = y, sq = y * y;
    #pragma unroll
    for (int off = 32; off > 0; off >>= 1) {
      sm += __shfl_xor(sm, off);
      sq += __shfl_xor(sq, off);
    }
    if (ln == 0) { red[pi * 16 + wv] = sm; red[pi * 16 + 8 + wv] = sq; }
  }
  __syncthreads();

  const float gam = gamma[d], bet = beta[d];
  #pragma unroll
  for (int pi = 0; pi < 4; ++pi) {
    float sum = 0.f, sumsq = 0.f;
    #pragma unroll
    for (int j = 0; j < 8; ++j) { sum += red[pi * 16 + j]; sumsq += red[pi * 16 + 8 + j]; }
    const float mu = sum * (1.f / 512.f);
    const float var = sumsq * (1.f / 512.f) - mu * mu;
    const float rs = rsqrtf(var + 1e-5f);
    const int p = pg * 4 + pi;
    out[((b << 6) + p) * 512 + d] = gam * (yv[pi] - mu) * rs + bet;
  }
}

extern "C" void kernel_launch(void* const* d_in, const int* in_sizes, int n_in,
                              void* d_out, int out_size, void* d_ws, size_t ws_size,
                              hipStream_t stream) {
  const float* x     = (const float*)d_in[0];
  const float* W1    = (const float*)d_in[1];
  const float* W2    = (const float*)d_in[2];
  const float* pw    = (const float*)d_in[3];
  const float* pb    = (const float*)d_in[4];
  const float* gamma = (const float*)d_in[5];
  const float* beta  = (const float*)d_in[6];
  float* out = (float*)d_out;

  char* ws = (char*)d_ws;
  unsigned short* X1kd = (unsigned short*)(ws);                          // 2MB [32][64][512]
  unsigned short* X2kd = (unsigned short*)(ws + (2u << 20));             // 2MB [32][64][512]
  unsigned short* W1t  = (unsigned short*)(ws + (4u << 20));             // 512KB swz
  unsigned short* W2t  = (unsigned short*)(ws + (4u << 20) + (512u << 10));

  transpose_w<<<dim3(128), dim3(256), 0, stream>>>(W1, W2, W1t, W2t);
  fused_layers<<<dim3(512), dim3(256), 69632, stream>>>(x, W1t, W2t, X1kd, X2kd);
  proj_ln<<<dim3(512), dim3(512), 0, stream>>>(x, X1kd, X2kd, pw, pb, gamma, beta, out);
}